// Round 10
// baseline (203.925 us; speedup 1.0000x reference)
//
#include <hip/hip_runtime.h>
#include <hip/hip_bf16.h>

typedef __attribute__((ext_vector_type(8))) short short8;
typedef __attribute__((ext_vector_type(4))) float f32x4;
typedef __attribute__((ext_vector_type(2))) unsigned int uint2v;
typedef __attribute__((ext_vector_type(4))) unsigned int uint4v;
typedef unsigned short u16;

#define MFMA_BF16(a, b, c) __builtin_amdgcn_mfma_f32_16x16x32_bf16(a, b, c, 0, 0, 0)

#define T_SEQ 2048
#define DMODEL 1024
#define NHEADS 16
#define DHEAD 64
#define NEG_BIG (-30000.0f)
#define QSCALE 0.1803368801111f  // 0.125 * log2(e): softmax in exp2 domain

#define EXP2(x) exp2f(x)

__device__ __forceinline__ unsigned bfr(unsigned u) {
  return (u + 0x7fffu + ((u >> 16) & 1u)) >> 16;
}
__device__ __forceinline__ uint4v ld8bf(const float* __restrict__ p) {
  const uint4v a = *(const uint4v*)p;
  const uint4v b = *(const uint4v*)(p + 4);
  uint4v r;
  r[0] = bfr(a[0]) | (bfr(a[1]) << 16);
  r[1] = bfr(a[2]) | (bfr(a[3]) << 16);
  r[2] = bfr(b[0]) | (bfr(b[1]) << 16);
  r[3] = bfr(b[2]) | (bfr(b[3]) << 16);
  return r;
}
__device__ __forceinline__ u16 f2bf(float f) {
  unsigned u = __float_as_uint(f);
  u += 0x7fffu + ((u >> 16) & 1u);
  return (u16)(u >> 16);
}
__device__ __forceinline__ void gld16(const u16* g, u16* l) {
  __builtin_amdgcn_global_load_lds(
      (const __attribute__((address_space(1))) unsigned int*)g,
      (__attribute__((address_space(3))) unsigned int*)l, 16, 0, 0);
}

// ---------------------------------------------------------------- cvt fp32->bf16
__global__ __launch_bounds__(256) void cvt_all(
    const float* __restrict__ x, const float* __restrict__ wq,
    const float* __restrict__ wk, const float* __restrict__ wv,
    const float* __restrict__ wo, u16* __restrict__ xh, u16* __restrict__ wqh,
    u16* __restrict__ wkh, u16* __restrict__ wvh, u16* __restrict__ woh) {
  int bi = blockIdx.x;
  const float* s;
  u16* d;
  size_t base;
  if (bi < 2048) {
    s = x; d = xh; base = (size_t)bi * 2048;
  } else {
    int k = (bi - 2048) >> 9;
    int r = (bi - 2048) & 511;
    s = (k == 0) ? wq : (k == 1) ? wk : (k == 2) ? wv : wo;
    d = (k == 0) ? wqh : (k == 1) ? wkh : (k == 2) ? wvh : woh;
    base = (size_t)r * 2048;
  }
  size_t i = base + (size_t)threadIdx.x * 8;
  *(uint4v*)&d[i] = ld8bf(&s[i]);
}

// ---------------------------------------------------------------- QKV proj (bf16)
// grid (32,8,3): z=0 Q (pre-scaled QSCALE) -> (b,h,t,d); z=1 K -> (b,h,t,d);
// z=2 V -> transposed (b,h,d,t). Swapped-operand MFMA for z<2 so lanes hold
// 4 consecutive d -> packed b64 stores; normal orientation for V packs along t.
__global__ __launch_bounds__(256) void gemm_qkv(
    const u16* __restrict__ X, const u16* __restrict__ Wq,
    const u16* __restrict__ Wk, const u16* __restrict__ Wv,
    u16* __restrict__ Qo, u16* __restrict__ Ko, u16* __restrict__ Vo) {
  __shared__ __attribute__((aligned(16))) u16 As[128 * 32];
  __shared__ __attribute__((aligned(16))) u16 Bs[128 * 32];
  const int tid = threadIdx.x, lane = tid & 63, w = tid >> 6;
  const int wm = (w >> 1) * 64, wn = (w & 1) * 64;
  const int lrow = lane & 15;
  const int quad = lane >> 4;
  const int lk = quad << 3;
  const int lq = quad << 2;
  const int mBase = blockIdx.x * 128, nBase = blockIdx.y * 128;
  const u16* Bt = (blockIdx.z == 0) ? Wq : (blockIdx.z == 1) ? Wk : Wv;
  u16* D = (blockIdx.z == 0) ? Qo : (blockIdx.z == 1) ? Ko : Vo;
  const float scale = (blockIdx.z == 0) ? QSCALE : 1.0f;
  const int vz = (blockIdx.z == 2);

  f32x4 acc[4][4];
#pragma unroll
  for (int mi = 0; mi < 4; mi++)
#pragma unroll
    for (int ni = 0; ni < 4; ni++) acc[mi][ni] = (f32x4)0.0f;

  for (int k0 = 0; k0 < 1024; k0 += 32) {
    __syncthreads();
#pragma unroll
    for (int i = 0; i < 2; i++) {
      int c = i * 256 + tid;
      int r = c >> 2, kk = (c & 3) << 3;
      gld16(&X[(size_t)(mBase + r) * 1024 + k0 + kk], &As[c * 8]);
      gld16(&Bt[(size_t)(nBase + r) * 1024 + k0 + kk], &Bs[c * 8]);
    }
    __syncthreads();
    short8 af[4], bf[4];
#pragma unroll
    for (int mi = 0; mi < 4; mi++)
      af[mi] = *(const short8*)&As[(wm + mi * 16 + lrow) * 32 + lk];
#pragma unroll
    for (int ni = 0; ni < 4; ni++)
      bf[ni] = *(const short8*)&Bs[(wn + ni * 16 + lrow) * 32 + lk];
    if (!vz) {  // C^T: lane col = m (af row), reg row = n (bf row)
#pragma unroll
      for (int mi = 0; mi < 4; mi++)
#pragma unroll
        for (int ni = 0; ni < 4; ni++)
          acc[mi][ni] = MFMA_BF16(bf[ni], af[mi], acc[mi][ni]);
    } else {    // normal: lane col = n, reg row = m
#pragma unroll
      for (int mi = 0; mi < 4; mi++)
#pragma unroll
        for (int ni = 0; ni < 4; ni++)
          acc[mi][ni] = MFMA_BF16(af[mi], bf[ni], acc[mi][ni]);
    }
  }

  if (!vz) {  // Q/K -> (b,h,t,d): lane m fixed, 4 consecutive dd per tile
#pragma unroll
    for (int mi = 0; mi < 4; mi++) {
      int m = mBase + wm + mi * 16 + lrow;
      int b = m >> 11, t = m & 2047;
#pragma unroll
      for (int ni = 0; ni < 4; ni++) {
        int n0 = nBase + wn + ni * 16 + lq;
        int h = n0 >> 6, dd = n0 & 63;
        uint2v pk;
        pk[0] = (unsigned)f2bf(acc[mi][ni][0] * scale) |
                ((unsigned)f2bf(acc[mi][ni][1] * scale) << 16);
        pk[1] = (unsigned)f2bf(acc[mi][ni][2] * scale) |
                ((unsigned)f2bf(acc[mi][ni][3] * scale) << 16);
        *(uint2v*)&D[(((size_t)(b * NHEADS + h)) * T_SEQ + t) * DHEAD + dd] = pk;
      }
    }
  } else {  // V -> (b,h,d,t): lane n fixed, 4 consecutive t per tile
#pragma unroll
    for (int mi = 0; mi < 4; mi++) {
      int m0 = mBase + wm + mi * 16 + lq;
      int b = m0 >> 11, t0 = m0 & 2047;
#pragma unroll
      for (int ni = 0; ni < 4; ni++) {
        int n = nBase + wn + ni * 16 + lrow;
        int h = n >> 6, dd = n & 63;
        uint2v pk;
        pk[0] = (unsigned)f2bf(acc[mi][ni][0]) |
                ((unsigned)f2bf(acc[mi][ni][1]) << 16);
        pk[1] = (unsigned)f2bf(acc[mi][ni][2]) |
                ((unsigned)f2bf(acc[mi][ni][3]) << 16);
        *(uint2v*)&D[((size_t)((b * NHEADS + h) * DHEAD + dd)) * T_SEQ + t0] = pk;
      }
    }
  }
}

// ---------------------------------------------------------------- attention
// grid (32=bh, 16=pair j): flat = j*32+bh -> XCD ~ bh%8, so each head's K/V
// stays in one XCD's L2. Snake: block handles q-tiles {j, 31-j} (64 rows each,
// 17 kv128-iters total). 4 waves, wave owns 16 q-rows. S^T formulation;
// per-lane softmax stats; kv-tile = 128.
__global__ __launch_bounds__(256) void attn_snake(
    const u16* __restrict__ Qg, const u16* __restrict__ Kg,
    const u16* __restrict__ Vtg, u16* __restrict__ Ob) {
  __shared__ __attribute__((aligned(16))) u16 smem[26624];  // 53248 B
  u16* Ks = smem;           // 128*72
  u16* Vt = smem + 9216;    // 64*136 (Vt[d][kv])
  u16* Ps = smem + 17920;   // 64*136
  u16* Qs = Ps;             // 64*72, staged before kv loop (alias)

  const int tid = threadIdx.x;
  const int w = tid >> 6, lane = tid & 63;
  const int lrow = lane & 15;
  const int quad = lane >> 4;
  const int lk = quad << 3;
  const int q_local = w * 16 + lrow;

  const int bh = blockIdx.x;  // 0..31
  const int j = blockIdx.y;   // 0..15
  const int b = bh >> 4, h = bh & 15;
  const u16* Qp = Qg + (size_t)bh * T_SEQ * DHEAD;
  const u16* Kp = Kg + (size_t)bh * T_SEQ * DHEAD;
  const u16* Vp = Vtg + (size_t)bh * DHEAD * T_SEQ;

#pragma unroll
  for (int p = 0; p < 2; p++) {
    const int qt = p ? (31 - j) : j;
    const int qb = qt * 64;

    __syncthreads();  // prior phase's LDS readers done
#pragma unroll
    for (int i = 0; i < 2; i++) {  // stage Q (64x64)
      int c = i * 256 + tid;
      int r = c >> 3, kk = (c & 7) << 3;
      *(uint4v*)&Qs[r * 72 + kk] =
          *(const uint4v*)&Qp[(size_t)(qb + r) * DHEAD + kk];
    }
    __syncthreads();
    short8 qf[2];
#pragma unroll
    for (int ks = 0; ks < 2; ks++)
      qf[ks] = *(const short8*)&Qs[q_local * 72 + ks * 32 + lk];

    float mst = NEG_BIG, lst = 0.f;
    f32x4 oacc[4];
#pragma unroll
    for (int nd = 0; nd < 4; nd++) oacc[nd] = (f32x4)0.0f;

    const int ntiles = (qt >> 1) + 1;
    for (int kt = 0; kt < ntiles; kt++) {
      const int kvb = kt * 128;
      __syncthreads();  // prior kf/vf/Ps readers done (qf loaded pre-loop)
#pragma unroll
      for (int i = 0; i < 4; i++) {  // K: 128 rows x 8 chunks
        int c = i * 256 + tid;
        int r = c >> 3, kk = (c & 7) << 3;
        *(uint4v*)&Ks[r * 72 + kk] =
            *(const uint4v*)&Kp[(size_t)(kvb + r) * DHEAD + kk];
      }
#pragma unroll
      for (int i = 0; i < 4; i++) {  // V^T: 64 d-rows x 16 chunks
        int c = i * 256 + tid;
        int d = c >> 4, kk = (c & 15) << 3;
        *(uint4v*)&Vt[d * 136 + kk] =
            *(const uint4v*)&Vp[(size_t)d * T_SEQ + kvb + kk];
      }
      __syncthreads();

      // S^T: col=lane&15=q_local, row(quad*4+r)=kv
      f32x4 s[8];
#pragma unroll
      for (int kvt = 0; kvt < 8; kvt++) {
        f32x4 a = (f32x4)0.0f;
#pragma unroll
        for (int ks = 0; ks < 2; ks++) {
          short8 kf = *(const short8*)&Ks[(kvt * 16 + lrow) * 72 + ks * 32 + lk];
          a = MFMA_BF16(kf, qf[ks], a);
        }
        s[kvt] = a;
      }

      if (kt == ntiles - 1) {  // mask only on the diagonal kv128 tile
#pragma unroll
        for (int kvt = 0; kvt < 8; kvt++)
#pragma unroll
          for (int r = 0; r < 4; r++)
            if (kvb + kvt * 16 + quad * 4 + r > qb + q_local)
              s[kvt][r] = NEG_BIG;
      }

      // online softmax, per-lane scalar stats
      float mx = s[0][0];
#pragma unroll
      for (int kvt = 0; kvt < 8; kvt++)
#pragma unroll
        for (int r = 0; r < 4; r++) mx = fmaxf(mx, s[kvt][r]);
      mx = fmaxf(mx, __shfl_xor(mx, 16));
      mx = fmaxf(mx, __shfl_xor(mx, 32));
      float mn = fmaxf(mst, mx);
      float corr = EXP2(mst - mn);
      mst = mn;
      float ls = 0.f;
#pragma unroll
      for (int kvt = 0; kvt < 8; kvt++)
#pragma unroll
        for (int r = 0; r < 4; r++) {
          float pv = EXP2(s[kvt][r] - mn);
          s[kvt][r] = pv;
          ls += pv;
        }
      ls += __shfl_xor(ls, 16);
      ls += __shfl_xor(ls, 32);
      lst = corr * lst + ls;
#pragma unroll
      for (int nd = 0; nd < 4; nd++) oacc[nd] *= corr;

      // P store (bf16 truncation; P in [0,1]): 8 packed b64 per lane
#pragma unroll
      for (int kvt = 0; kvt < 8; kvt++) {
        uint2v pk;
        pk[0] = (__float_as_uint(s[kvt][0]) >> 16) |
                (__float_as_uint(s[kvt][1]) & 0xffff0000u);
        pk[1] = (__float_as_uint(s[kvt][2]) >> 16) |
                (__float_as_uint(s[kvt][3]) & 0xffff0000u);
        *(uint2v*)&Ps[q_local * 136 + kvt * 16 + quad * 4] = pk;
      }

      // O^T += V^T P^T over K=128
#pragma unroll
      for (int ks = 0; ks < 4; ks++) {
        short8 pf = *(const short8*)&Ps[q_local * 136 + ks * 32 + lk];
#pragma unroll
        for (int nd = 0; nd < 4; nd++) {
          short8 vf = *(const short8*)&Vt[(nd * 16 + lrow) * 136 + ks * 32 + lk];
          oacc[nd] = MFMA_BF16(vf, pf, oacc[nd]);
        }
      }
    }

    // epilogue: lane owns q-row qb+q_local; d = nd*16 + quad*4 + r
    float inv = 1.f / lst;
    size_t rowbase = ((size_t)(b * T_SEQ + qb + q_local)) * DMODEL + h * DHEAD;
#pragma unroll
    for (int nd = 0; nd < 4; nd++) {
      uint2v pk;
      pk[0] = (unsigned)f2bf(oacc[nd][0] * inv) |
              ((unsigned)f2bf(oacc[nd][1] * inv) << 16);
      pk[1] = (unsigned)f2bf(oacc[nd][2] * inv) |
              ((unsigned)f2bf(oacc[nd][3] * inv) << 16);
      *(uint2v*)&Ob[rowbase + nd * 16 + quad * 4] = pk;
    }
  }
}

// ---------------------------------------------------------------- out proj (bf16)
// Swapped-operand MFMA -> lane holds 4 consecutive n -> float4 stores.
__global__ __launch_bounds__(256) void gemm_out_bf(const u16* __restrict__ O,
                                                   const u16* __restrict__ Wo,
                                                   float* __restrict__ Out) {
  __shared__ __attribute__((aligned(16))) u16 As[128 * 32];
  __shared__ __attribute__((aligned(16))) u16 Bs[128 * 32];
  const int tid = threadIdx.x, lane = tid & 63, w = tid >> 6;
  const int wm = (w >> 1) * 64, wn = (w & 1) * 64;
  const int lrow = lane & 15;
  const int quad = lane >> 4;
  const int lk = quad << 3;
  const int mBase = blockIdx.x * 128, nBase = blockIdx.y * 128;

  f32x4 acc[4][4];
#pragma unroll
  for (int mi = 0; mi < 4; mi++)
#pragma unroll
    for (int ni = 0; ni < 4; ni++) acc[mi][ni] = (f32x4)0.0f;

  for (int k0 = 0; k0 < 1024; k0 += 32) {
    __syncthreads();
#pragma unroll
    for (int i = 0; i < 2; i++) {
      int c = i * 256 + tid;
      int r = c >> 2, kk = (c & 3) << 3;
      gld16(&O[(size_t)(mBase + r) * 1024 + k0 + kk], &As[c * 8]);
      gld16(&Wo[(size_t)(nBase + r) * 1024 + k0 + kk], &Bs[c * 8]);
    }
    __syncthreads();
    short8 af[4], bf[4];
#pragma unroll
    for (int mi = 0; mi < 4; mi++)
      af[mi] = *(const short8*)&As[(wm + mi * 16 + lrow) * 32 + lk];
#pragma unroll
    for (int ni = 0; ni < 4; ni++)
      bf[ni] = *(const short8*)&Bs[(wn + ni * 16 + lrow) * 32 + lk];
#pragma unroll
    for (int mi = 0; mi < 4; mi++)
#pragma unroll
      for (int ni = 0; ni < 4; ni++)
        acc[mi][ni] = MFMA_BF16(bf[ni], af[mi], acc[mi][ni]);  // C^T
  }
#pragma unroll
  for (int mi = 0; mi < 4; mi++) {
    int m = mBase + wm + mi * 16 + lrow;
#pragma unroll
    for (int ni = 0; ni < 4; ni++) {
      int n0 = nBase + wn + ni * 16 + (quad << 2);
      *(f32x4*)&Out[(size_t)m * DMODEL + n0] = acc[mi][ni];
    }
  }
}

// ---------------------------------------------------------------- launch
extern "C" void kernel_launch(void* const* d_in, const int* in_sizes, int n_in,
                              void* d_out, int out_size, void* d_ws,
                              size_t ws_size, hipStream_t stream) {
  const float* x = (const float*)d_in[0];
  const float* Wq = (const float*)d_in[1];
  const float* Wk = (const float*)d_in[2];
  const float* Wv = (const float*)d_in[3];
  const float* Wo = (const float*)d_in[4];
  float* out = (float*)d_out;

  u16* xh = (u16*)d_ws;      // 4M elems
  u16* wqh = xh + 4194304;   // 1M each
  u16* wkh = wqh + 1048576;
  u16* wvh = wkh + 1048576;
  u16* woh = wvh + 1048576;
  u16* Q = woh + 1048576;    // 4M each; V stored transposed (b,h,d,t)
  u16* K = Q + 4194304;
  u16* V = K + 4194304;
  u16* O = V + 4194304;      // total 48 MB

  cvt_all<<<dim3(4096), 256, 0, stream>>>(x, Wq, Wk, Wv, Wo, xh, wqh, wkh, wvh, woh);
  gemm_qkv<<<dim3(32, 8, 3), 256, 0, stream>>>(xh, wqh, wkh, wvh, Q, K, V);
  attn_snake<<<dim3(32, 16), 256, 0, stream>>>(Q, K, V, O);
  gemm_out_bf<<<dim3(32, 8), 256, 0, stream>>>(O, woh, out);
}